// Round 7
// baseline (257.318 us; speedup 1.0000x reference)
//
#include <hip/hip_runtime.h>
#include <hip/hip_bf16.h>

#define BB 8
#define NN 2048
#define FIN 128
#define FO 64
#define ALPHA 0.2f

typedef __attribute__((ext_vector_type(8))) short bf16x8;
typedef __attribute__((ext_vector_type(4))) float f32x4;
typedef __attribute__((ext_vector_type(4))) int i32x4;

typedef __attribute__((address_space(1))) const void gvoid;
typedef __attribute__((address_space(3))) void lvoid;

__device__ inline void gl_lds16(const void* g, void* l) {
    // async global->LDS, 16B per lane; LDS dest = uniform base + lane*16
    __builtin_amdgcn_global_load_lds((gvoid*)g, (lvoid*)l, 16, 0, 0);
}

__device__ inline short f2bf(float x) {
    unsigned u = __float_as_uint(x);
    u += 0x7fffu + ((u >> 16) & 1u);   // RNE, sign-agnostic, no NaN inputs here
    return (short)(u >> 16);
}

// ---------------- Kernel A: Wh = h@W; whF in MFMA B-fragment layout ----------
// whF[b][jc][ot][lane][8] shorts: lane L holds Wh[b][j=jc*32+(L>>4)*8+jj][o=ot*16+(L&15)]
// h rows are wave-uniform -> scalar (K$) loads; no LDS, no barrier.
// e2 maxes: ONE non-atomic float store per wave into e2p[b][0..255].
__global__ __launch_bounds__(256) void wh_kernel(
    const float* __restrict__ h, const float* __restrict__ W,
    const float* __restrict__ a, float* __restrict__ e1, float* __restrict__ e2,
    float* __restrict__ e2p, short* __restrict__ whF)
{
    const int t  = threadIdx.x;
    const int o  = t & 63;
    const int wv = t >> 6;                     // rows wv*8 .. wv*8+7
    const int r0 = blockIdx.x * 32;            // 32 rows per block (same batch)
    const float* __restrict__ hrow =
        h + (size_t)(r0 + __builtin_amdgcn_readfirstlane(wv) * 8) * FIN;

    float acc[8];
#pragma unroll
    for (int rr = 0; rr < 8; rr++) acc[rr] = 0.f;

    for (int f = 0; f < FIN; f += 4) {
        const float w0 = W[(f + 0) * FO + o];
        const float w1 = W[(f + 1) * FO + o];
        const float w2 = W[(f + 2) * FO + o];
        const float w3 = W[(f + 3) * FO + o];
#pragma unroll
        for (int rr = 0; rr < 8; rr++) {
            const float4 hv = *(const float4*)(hrow + rr * FIN + f);  // uniform -> SGPR
            acc[rr] = fmaf(hv.x, w0, acc[rr]);
            acc[rr] = fmaf(hv.y, w1, acc[rr]);
            acc[rr] = fmaf(hv.z, w2, acc[rr]);
            acc[rr] = fmaf(hv.w, w3, acc[rr]);
        }
    }

    const int b   = r0 / NN;
    const int ib0 = r0 - b * NN;
    const int ibb = ib0 + wv * 8;
    const int jc  = ibb >> 5;
    const int qq  = (ibb >> 3) & 3;
    const int ot  = o >> 4, mm = o & 15;
    const int L   = mm + qq * 16;
    bf16x8 frag;
#pragma unroll
    for (int rr = 0; rr < 8; rr++) frag[rr] = f2bf(acc[rr]);
    *(bf16x8*)(whF + ((((size_t)(b * 64 + jc) * 4 + ot) * 64 + L) * 8)) = frag;

    const float a1 = a[o], a2 = a[FO + o];
    float vmax = -3.0e38f;
#pragma unroll
    for (int rr = 0; rr < 8; rr++) {
        float v1 = acc[rr] * a1, v2 = acc[rr] * a2;
#pragma unroll
        for (int msk = 32; msk >= 1; msk >>= 1) {
            v1 += __shfl_xor(v1, msk, 64);
            v2 += __shfl_xor(v2, msk, 64);
        }
        vmax = fmaxf(vmax, v2);
        if (o == 0) { e1[r0 + wv * 8 + rr] = v1; e2[r0 + wv * 8 + rr] = v2; }
    }
    if (o == 0) e2p[b * 256 + (ib0 >> 5) * 4 + wv] = vmax;
}

// ---------------- Kernel B: attention partial, R0 structure + j-split -------
// Ladder evidence (attn us): R0 naive-drain 52 < R3 counted 58 < R5 regpipe 70
// ~= R6 deepstage 72 -> in-block pipelining is NEGATIVE value; cross-block TLP
// is the latency-hiding mechanism.  So: keep the proven R0 schedule verbatim
// (gl_lds16 stage + __syncthreads drain per 256-col tile) and DOUBLE the
// number of independent block streams via j-split: grid 1024 -> 2048, each
// block does half the j-range (4 tiles) and writes unnormalized partials.
// Both halves use the same deterministic mi -> partials add exactly.
// LDS 17.7KB, launch_bounds(256,8) -> 8 blocks/CU (32 waves, was 16).
struct SMemS { int adj[16][260]; float e2[256]; };
struct SMemC { float comb[4][16][64]; float lsum[4][16]; };
union __align__(16) SMemU { SMemS s; SMemC c; };       // 17664 B

__global__ __launch_bounds__(256, 8) void attn_kernel(
    const int* __restrict__ adj, const float* __restrict__ e1,
    const float* __restrict__ e2, const float* __restrict__ e2p,
    const short* __restrict__ whF, float* __restrict__ pacc,
    float* __restrict__ plsum)
{
    __shared__ SMemU sm;
    __shared__ float red4[4];
    const int t = threadIdx.x, w = t >> 6, lane = t & 63;
    const int m = lane & 15, q = lane >> 4;
    const int blk = blockIdx.x;
    const int jh  = blk >> 10;                 // j half: 0 or 1
    const int tb  = blk & 1023;                // (b, i-tile)
    const int b   = tb >> 7;
    const int i0  = (tb & 127) * 16;
    const int i   = i0 + m;

    // ---- batch e2max from per-wave partials (256 floats, L2-resident) ----
    float pv = e2p[b * 256 + t];
    const float e1v = e1[b * NN + i];
#pragma unroll
    for (int k = 32; k >= 1; k >>= 1) pv = fmaxf(pv, __shfl_xor(pv, k, 64));
    if (lane == 0) red4[w] = pv;
    __syncthreads();
    const float e2mx = fmaxf(fmaxf(red4[0], red4[1]), fmaxf(red4[2], red4[3]));

    float mi = e1v + e2mx;
    mi = mi > 0.f ? mi : ALPHA * mi;           // same in both j-halves (deterministic)

    const short* whFb = whF + (size_t)b * (64 * 4 * 64 * 8);
    const int* arow0 = adj + ((size_t)(b * NN + i0)) * NN + lane * 4;  // lane's 16B of a row
    const float* e2g = e2 + b * NN + lane * 4;
    const int jbase = jh * 1024;

    f32x4 acc0 = {0.f,0.f,0.f,0.f}, acc1 = acc0, acc2 = acc0, acc3 = acc0;
    float lsum = 0.f;

    for (int tt = 0; tt < 4; tt++) {
        const int j0 = jbase + tt * 256;
        // stage adj[16][256] (1KB per wave-instruction) + e2[256]
#pragma unroll
        for (int k = 0; k < 4; k++) {
            const int r = w * 4 + k;
            gl_lds16(arow0 + (size_t)r * NN + j0, &sm.s.adj[r][0]);
        }
        if (w == 0) gl_lds16(e2g + j0, &sm.s.e2[0]);
        __syncthreads();                       // drain; cross-block TLP hides it

#pragma unroll
        for (int s2 = 0; s2 < 2; s2++) {
            const int col = w * 64 + s2 * 32 + q * 8;
            i32x4 a0 = *(const i32x4*)&sm.s.adj[m][col];
            i32x4 a1 = *(const i32x4*)&sm.s.adj[m][col + 4];
            f32x4 ev0 = *(const f32x4*)&sm.s.e2[col];
            f32x4 ev1 = *(const f32x4*)&sm.s.e2[col + 4];

            bf16x8 af;
#pragma unroll
            for (int jj = 0; jj < 8; jj++) {
                const int   av  = (jj < 4) ? a0[jj]      : a1[jj - 4];
                const float e2j = (jj < 4) ? ev0[jj]     : ev1[jj - 4];
                float e = e1v + e2j;
                e = e > 0.f ? e : ALPHA * e;
                const float pe = (av > 0) ? __expf(e - mi) : 0.f;
                lsum += pe;
                af[jj] = f2bf(pe);
            }

            const int jc = (j0 + w * 64 + s2 * 32) >> 5;   // GLOBAL j chunk
            const short* bfp = whFb + (size_t)jc * 2048 + lane * 8;
            bf16x8 b0 = *(const bf16x8*)(bfp);
            bf16x8 b1 = *(const bf16x8*)(bfp + 512);
            bf16x8 b2 = *(const bf16x8*)(bfp + 1024);
            bf16x8 b3 = *(const bf16x8*)(bfp + 1536);

            acc0 = __builtin_amdgcn_mfma_f32_16x16x32_bf16(af, b0, acc0, 0, 0, 0);
            acc1 = __builtin_amdgcn_mfma_f32_16x16x32_bf16(af, b1, acc1, 0, 0, 0);
            acc2 = __builtin_amdgcn_mfma_f32_16x16x32_bf16(af, b2, acc2, 0, 0, 0);
            acc3 = __builtin_amdgcn_mfma_f32_16x16x32_bf16(af, b3, acc3, 0, 0, 0);
        }
        __syncthreads();   // protect LDS reuse (stage of next tile / combine)
    }

    // cross-wave combine in LDS (union reuse; last barrier above fences it)
    lsum += __shfl_xor(lsum, 16, 64);
    lsum += __shfl_xor(lsum, 32, 64);
    if (q == 0) sm.c.lsum[w][m] = lsum;
#pragma unroll
    for (int ot = 0; ot < 4; ot++) {
        f32x4 av = (ot == 0) ? acc0 : (ot == 1) ? acc1 : (ot == 2) ? acc2 : acc3;
#pragma unroll
        for (int reg = 0; reg < 4; reg++)
            sm.c.comb[w][q * 4 + reg][ot * 16 + m] = av[reg];
    }
    __syncthreads();

    // write UNNORMALIZED partials for this j-half
    const int row = t >> 4, c0 = (t & 15) * 4;
    f32x4 sum = *(const f32x4*)&sm.c.comb[0][row][c0];
#pragma unroll
    for (int ww = 1; ww < 4; ww++) {
        f32x4 sv = *(const f32x4*)&sm.c.comb[ww][row][c0];
        sum.x += sv.x; sum.y += sv.y; sum.z += sv.z; sum.w += sv.w;
    }
    *(f32x4*)&pacc[((size_t)blk * 16 + row) * 64 + c0] = sum;
    if ((t & 15) == 0) {
        plsum[blk * 16 + row] = sm.c.lsum[0][row] + sm.c.lsum[1][row]
                              + sm.c.lsum[2][row] + sm.c.lsum[3][row];
    }
}

// ---------------- Kernel C: combine j-halves, normalize, ELU ----------------
__global__ __launch_bounds__(256) void comb_kernel(
    const float* __restrict__ pacc, const float* __restrict__ plsum,
    float* __restrict__ out)
{
    const int tb = blockIdx.x;                 // (b, i-tile)
    const int t = threadIdx.x;
    const int row = t >> 4, c0 = (t & 15) * 4;
    const int b = tb >> 7;
    const int i0 = (tb & 127) * 16;

    f32x4 s0 = *(const f32x4*)&pacc[((size_t)tb * 16 + row) * 64 + c0];
    f32x4 s1 = *(const f32x4*)&pacc[((size_t)(1024 + tb) * 16 + row) * 64 + c0];
    float l = plsum[tb * 16 + row] + plsum[(1024 + tb) * 16 + row];
    l = fmaxf(l, 1e-30f);
    const float rl = 1.f / l;
    f32x4 res;
#pragma unroll
    for (int k = 0; k < 4; k++) {
        const float v = (s0[k] + s1[k]) * rl;
        res[k] = v > 0.f ? v : (__expf(v) - 1.f);
    }
    *(f32x4*)&out[((size_t)(b * NN + i0 + row)) * FO + c0] = res;
}

extern "C" void kernel_launch(void* const* d_in, const int* in_sizes, int n_in,
                              void* d_out, int out_size, void* d_ws, size_t ws_size,
                              hipStream_t stream) {
    const float* h   = (const float*)d_in[0];
    const int*   adj = (const int*)d_in[1];
    const float* W   = (const float*)d_in[2];
    const float* a   = (const float*)d_in[3];
    float* out = (float*)d_out;

    char* ws = (char*)d_ws;
    short* whF = (short*)ws;                                   // 2 MB
    size_t off = (size_t)BB * 64 * 4 * 64 * 8 * sizeof(short);
    float* e1  = (float*)(ws + off);  off += (size_t)BB * NN * 4;
    float* e2  = (float*)(ws + off);  off += (size_t)BB * NN * 4;
    float* e2p = (float*)(ws + off);  off += (size_t)BB * 256 * 4;
    float* pacc  = (float*)(ws + off); off += (size_t)2048 * 16 * 64 * 4;  // 8 MB
    float* plsum = (float*)(ws + off);                                     // 128 KB

    wh_kernel<<<(BB * NN) / 32, 256, 0, stream>>>(h, W, a, e1, e2, e2p, whF);
    attn_kernel<<<2048, 256, 0, stream>>>(adj, e1, e2, e2p, whF, pacc, plsum);
    comb_kernel<<<1024, 256, 0, stream>>>(pacc, plsum, out);
}

// Round 8
// 224.789 us; speedup vs baseline: 1.1447x; 1.1447x over previous
//
#include <hip/hip_runtime.h>
#include <hip/hip_bf16.h>

#define BB 8
#define NN 2048
#define FIN 128
#define FO 64
#define ALPHA 0.2f

typedef __attribute__((ext_vector_type(8))) short bf16x8;
typedef __attribute__((ext_vector_type(4))) float f32x4;
typedef __attribute__((ext_vector_type(4))) int i32x4;

typedef __attribute__((address_space(1))) const void gvoid;
typedef __attribute__((address_space(3))) void lvoid;

__device__ inline void gl_lds16(const void* g, void* l) {
    // async global->LDS, 16B per lane; LDS dest = uniform base + lane*16
    __builtin_amdgcn_global_load_lds((gvoid*)g, (lvoid*)l, 16, 0, 0);
}

__device__ inline short f2bf(float x) {
    unsigned u = __float_as_uint(x);
    u += 0x7fffu + ((u >> 16) & 1u);   // RNE, sign-agnostic, no NaN inputs here
    return (short)(u >> 16);
}

// ---------------- Kernel A: Wh = h@W; whF in MFMA B-fragment layout ----------
// whF[b][jc][ot][lane][8] shorts: lane L holds Wh[b][j=jc*32+(L>>4)*8+jj][o=ot*16+(L&15)]
// h rows are wave-uniform -> scalar (K$) loads; no LDS, no barrier.
// e2 maxes: ONE non-atomic float store per wave into e2p[b][0..255].
__global__ __launch_bounds__(256) void wh_kernel(
    const float* __restrict__ h, const float* __restrict__ W,
    const float* __restrict__ a, float* __restrict__ e1, float* __restrict__ e2,
    float* __restrict__ e2p, short* __restrict__ whF)
{
    const int t  = threadIdx.x;
    const int o  = t & 63;
    const int wv = t >> 6;                     // rows wv*8 .. wv*8+7
    const int r0 = blockIdx.x * 32;            // 32 rows per block (same batch)
    const float* __restrict__ hrow =
        h + (size_t)(r0 + __builtin_amdgcn_readfirstlane(wv) * 8) * FIN;

    float acc[8];
#pragma unroll
    for (int rr = 0; rr < 8; rr++) acc[rr] = 0.f;

    for (int f = 0; f < FIN; f += 4) {
        const float w0 = W[(f + 0) * FO + o];
        const float w1 = W[(f + 1) * FO + o];
        const float w2 = W[(f + 2) * FO + o];
        const float w3 = W[(f + 3) * FO + o];
#pragma unroll
        for (int rr = 0; rr < 8; rr++) {
            const float4 hv = *(const float4*)(hrow + rr * FIN + f);  // uniform -> SGPR
            acc[rr] = fmaf(hv.x, w0, acc[rr]);
            acc[rr] = fmaf(hv.y, w1, acc[rr]);
            acc[rr] = fmaf(hv.z, w2, acc[rr]);
            acc[rr] = fmaf(hv.w, w3, acc[rr]);
        }
    }

    const int b   = r0 / NN;
    const int ib0 = r0 - b * NN;
    const int ibb = ib0 + wv * 8;
    const int jc  = ibb >> 5;
    const int qq  = (ibb >> 3) & 3;
    const int ot  = o >> 4, mm = o & 15;
    const int L   = mm + qq * 16;
    bf16x8 frag;
#pragma unroll
    for (int rr = 0; rr < 8; rr++) frag[rr] = f2bf(acc[rr]);
    *(bf16x8*)(whF + ((((size_t)(b * 64 + jc) * 4 + ot) * 64 + L) * 8)) = frag;

    const float a1 = a[o], a2 = a[FO + o];
    float vmax = -3.0e38f;
#pragma unroll
    for (int rr = 0; rr < 8; rr++) {
        float v1 = acc[rr] * a1, v2 = acc[rr] * a2;
#pragma unroll
        for (int msk = 32; msk >= 1; msk >>= 1) {
            v1 += __shfl_xor(v1, msk, 64);
            v2 += __shfl_xor(v2, msk, 64);
        }
        vmax = fmaxf(vmax, v2);
        if (o == 0) { e1[r0 + wv * 8 + rr] = v1; e2[r0 + wv * 8 + rr] = v2; }
    }
    if (o == 0) e2p[b * 256 + (ib0 >> 5) * 4 + wv] = vmax;
}

// ---------------- Kernel B: attention, R0 structure + 2KB adj spans ---------
// Ladder dataset, adj effective BW vs contiguous span length:
//   64B spans (R4 direct)    -> 1.6 TB/s
//   1KB spans (R0/R7 staged) -> 2.2-2.6 TB/s
//   sequential (harness fill)-> 6.9 TB/s
// Neither pipelining (R3/R5/R6) nor occupancy (R7: 77% occ, SLOWER) moved it
// -> the memory system itself runs ~2.5 TB/s for 1KB-strided streams (DRAM
// page/burst efficiency).  This round widens the span: tile 16x512, each row
// staged as 2KB contiguous (2 back-to-back gl_lds16), 4 stages instead of 8.
// Everything else is the empirically-best R0 shape: naive syncthreads drain,
// full j-range per block, direct normalized output.  LDS 35KB -> 4 blocks/CU.
struct SMemS { int adj[16][516]; float e2[512]; };     // row pad 516: same bank pattern as R0's 260
struct SMemC { float comb[4][16][64]; float lsum[4][16]; };
union __align__(16) SMemU { SMemS s; SMemC c; };       // 35072 B

__global__ __launch_bounds__(256, 4) void attn_kernel(
    const int* __restrict__ adj, const float* __restrict__ e1,
    const float* __restrict__ e2, const float* __restrict__ e2p,
    const short* __restrict__ whF, float* __restrict__ out)
{
    __shared__ SMemU sm;
    __shared__ float red4[4];
    const int t = threadIdx.x, w = t >> 6, lane = t & 63;
    const int m = lane & 15, q = lane >> 4;
    const int blk = blockIdx.x;
    const int b  = blk >> 7;
    const int i0 = (blk & 127) * 16;
    const int i  = i0 + m;

    // ---- batch e2max from per-wave partials (256 floats, L2-resident) ----
    float pv = e2p[b * 256 + t];
    const float e1v = e1[b * NN + i];
#pragma unroll
    for (int k = 32; k >= 1; k >>= 1) pv = fmaxf(pv, __shfl_xor(pv, k, 64));
    if (lane == 0) red4[w] = pv;
    __syncthreads();
    const float e2mx = fmaxf(fmaxf(red4[0], red4[1]), fmaxf(red4[2], red4[3]));

    float mi = e1v + e2mx;
    mi = mi > 0.f ? mi : ALPHA * mi;           // safe per-row max bound (leakyrelu monotone)

    const short* whFb = whF + (size_t)b * (64 * 4 * 64 * 8);
    // wave w stages rows i0+w*4 .. i0+w*4+3; each row: 2KB contiguous per tile
    const int* arow = adj + (size_t)(b * NN + i0 + w * 4) * NN + lane * 4;
    const float* e2g = e2 + b * NN + lane * 4;

    f32x4 acc0 = {0.f,0.f,0.f,0.f}, acc1 = acc0, acc2 = acc0, acc3 = acc0;
    float lsum = 0.f;

    for (int tt = 0; tt < 4; tt++) {
        const int j0 = tt * 512;
        // stage adj[16][512]: per row TWO back-to-back 1KB gl_lds16 ->
        // a 2KB sequential request train per row (the span-length lever)
#pragma unroll
        for (int rr = 0; rr < 4; rr++) {
            const int* src = arow + (size_t)rr * NN + j0;
            gl_lds16(src,        &sm.s.adj[w * 4 + rr][0]);
            gl_lds16(src + 256,  &sm.s.adj[w * 4 + rr][256]);
        }
        if (w == 0) {
            gl_lds16(e2g + j0,        &sm.s.e2[0]);
            gl_lds16(e2g + j0 + 256,  &sm.s.e2[256]);
        }
        __syncthreads();                       // naive drain (beat all pipelines)

#pragma unroll
        for (int s2 = 0; s2 < 4; s2++) {
            const int col = w * 128 + s2 * 32 + q * 8;
            i32x4 a0 = *(const i32x4*)&sm.s.adj[m][col];
            i32x4 a1 = *(const i32x4*)&sm.s.adj[m][col + 4];
            f32x4 ev0 = *(const f32x4*)&sm.s.e2[col];
            f32x4 ev1 = *(const f32x4*)&sm.s.e2[col + 4];

            bf16x8 af;
#pragma unroll
            for (int jj = 0; jj < 8; jj++) {
                const int   av  = (jj < 4) ? a0[jj]      : a1[jj - 4];
                const float e2j = (jj < 4) ? ev0[jj]     : ev1[jj - 4];
                float e = e1v + e2j;
                e = e > 0.f ? e : ALPHA * e;
                const float pe = (av > 0) ? __expf(e - mi) : 0.f;
                lsum += pe;
                af[jj] = f2bf(pe);
            }

            const int jc = (j0 + w * 128 + s2 * 32) >> 5;
            const short* bfp = whFb + (size_t)jc * 2048 + lane * 8;
            bf16x8 b0 = *(const bf16x8*)(bfp);
            bf16x8 b1 = *(const bf16x8*)(bfp + 512);
            bf16x8 b2 = *(const bf16x8*)(bfp + 1024);
            bf16x8 b3 = *(const bf16x8*)(bfp + 1536);

            acc0 = __builtin_amdgcn_mfma_f32_16x16x32_bf16(af, b0, acc0, 0, 0, 0);
            acc1 = __builtin_amdgcn_mfma_f32_16x16x32_bf16(af, b1, acc1, 0, 0, 0);
            acc2 = __builtin_amdgcn_mfma_f32_16x16x32_bf16(af, b2, acc2, 0, 0, 0);
            acc3 = __builtin_amdgcn_mfma_f32_16x16x32_bf16(af, b3, acc3, 0, 0, 0);
        }
        __syncthreads();   // protect LDS reuse (stage of next tile / combine)
    }

    // cross-wave combine in LDS (union reuse; last barrier above fences it)
    lsum += __shfl_xor(lsum, 16, 64);
    lsum += __shfl_xor(lsum, 32, 64);
    if (q == 0) sm.c.lsum[w][m] = lsum;
#pragma unroll
    for (int ot = 0; ot < 4; ot++) {
        f32x4 av = (ot == 0) ? acc0 : (ot == 1) ? acc1 : (ot == 2) ? acc2 : acc3;
#pragma unroll
        for (int reg = 0; reg < 4; reg++)
            sm.c.comb[w][q * 4 + reg][ot * 16 + m] = av[reg];
    }
    __syncthreads();

    const int row = t >> 4, c0 = (t & 15) * 4;
    f32x4 sum = *(const f32x4*)&sm.c.comb[0][row][c0];
#pragma unroll
    for (int ww = 1; ww < 4; ww++) {
        f32x4 sv = *(const f32x4*)&sm.c.comb[ww][row][c0];
        sum.x += sv.x; sum.y += sv.y; sum.z += sv.z; sum.w += sv.w;
    }
    float l = sm.c.lsum[0][row] + sm.c.lsum[1][row] + sm.c.lsum[2][row] + sm.c.lsum[3][row];
    l = fmaxf(l, 1e-30f);
    const float rl = 1.f / l;
    float vr[4] = { sum.x * rl, sum.y * rl, sum.z * rl, sum.w * rl };
    f32x4 res;
#pragma unroll
    for (int kk = 0; kk < 4; kk++)
        res[kk] = vr[kk] > 0.f ? vr[kk] : (__expf(vr[kk]) - 1.f);
    *(f32x4*)&out[((size_t)(b * NN + i0 + row)) * FO + c0] = res;
}

extern "C" void kernel_launch(void* const* d_in, const int* in_sizes, int n_in,
                              void* d_out, int out_size, void* d_ws, size_t ws_size,
                              hipStream_t stream) {
    const float* h   = (const float*)d_in[0];
    const int*   adj = (const int*)d_in[1];
    const float* W   = (const float*)d_in[2];
    const float* a   = (const float*)d_in[3];
    float* out = (float*)d_out;

    char* ws = (char*)d_ws;
    short* whF = (short*)ws;                                   // 2 MB
    size_t off = (size_t)BB * 64 * 4 * 64 * 8 * sizeof(short);
    float* e1  = (float*)(ws + off);  off += (size_t)BB * NN * 4;
    float* e2  = (float*)(ws + off);  off += (size_t)BB * NN * 4;
    float* e2p = (float*)(ws + off);                           // 8 x 256 partial maxes

    wh_kernel<<<(BB * NN) / 32, 256, 0, stream>>>(h, W, a, e1, e2, e2p, whF);
    attn_kernel<<<BB * (NN / 16), 256, 0, stream>>>(adj, e1, e2, e2p, whF, out);
}